// Round 1
// baseline (745.939 us; speedup 1.0000x reference)
//
#include <hip/hip_runtime.h>
#include <hip/hip_bf16.h>

#define BB 32
#define NN 128
#define SD 128
#define ED 32
#define ID 256
#define BN (BB*NN)   // 4096
#define TJ 16

__device__ __forceinline__ float ftanh(float x) {
    float xc = fminf(fmaxf(x, -9.0f), 9.0f);
    float e2 = __expf(2.0f * xc);
    return (e2 - 1.0f) * __builtin_amdgcn_rcpf(e2 + 1.0f);
}

// ---------------------------------------------------------------------------
// K1: node pre-projections  H{g,m}{i,j}[n,k] = h[n,:] @ W1[rows,k] (+bias for i)
// grid (BN/32, 4), block 256
// ---------------------------------------------------------------------------
__global__ void k1_preproj(const float* __restrict__ h,
                           const float* __restrict__ Wg1, const float* __restrict__ bg1,
                           const float* __restrict__ Wm1, const float* __restrict__ bm1,
                           float* __restrict__ Hgi, float* __restrict__ Hgj,
                           float* __restrict__ Hmi, float* __restrict__ Hmj) {
    const int tile = blockIdx.x;
    const int which = blockIdx.y;
    __shared__ float hs[32][SD];
    const int t = threadIdx.x;
    const float* hrow = h + (size_t)tile * 32 * SD;
    for (int i = t; i < 32 * SD; i += 256) hs[i >> 7][i & 127] = hrow[i];
    __syncthreads();
    const float* W; const float* bias = nullptr; float* out;
    if (which == 0)      { W = Wg1;           bias = bg1; out = Hgi; }
    else if (which == 1) { W = Wg1 + SD * ID;             out = Hgj; }
    else if (which == 2) { W = Wm1;           bias = bm1; out = Hmi; }
    else                 { W = Wm1 + SD * ID;             out = Hmj; }
    const int k = t;
    float acc[32];
    const float b0 = bias ? bias[k] : 0.0f;
    #pragma unroll
    for (int r = 0; r < 32; ++r) acc[r] = b0;
    for (int c = 0; c < SD; ++c) {
        const float wv = W[c * ID + k];
        #pragma unroll
        for (int r = 0; r < 32; ++r) acc[r] = fmaf(hs[r][c], wv, acc[r]);
    }
    #pragma unroll
    for (int r = 0; r < 32; ++r) out[(size_t)(tile * 32 + r) * ID + k] = acc[r];
}

// ---------------------------------------------------------------------------
// K2: per-(b,i) edge kernel. 4 waves split the 256 hidden dims (k = tid).
// We-columns in registers; e_ij wave-uniform; gate via shfl + LDS combine.
// Outputs T[b,i,256] = sum_j gate*tanh(z_m), gsum, degree.
// grid BN, block 256
// ---------------------------------------------------------------------------
__global__ void k2_edges(const float* __restrict__ ef, const float* __restrict__ em,
                         const float* __restrict__ Wg1, const float* __restrict__ Wm1,
                         const float* __restrict__ Wg2, const float* __restrict__ bg2,
                         const float* __restrict__ Hgi, const float* __restrict__ Hgj,
                         const float* __restrict__ Hmi, const float* __restrict__ Hmj,
                         float* __restrict__ T, float* __restrict__ gsum,
                         float* __restrict__ deg) {
    const int bi = blockIdx.x;
    const int b = bi >> 7;
    const int t = threadIdx.x;
    const int w = t >> 6;
    const int lane = t & 63;
    const int k = t;
    float wge[ED], wme[ED];
    #pragma unroll
    for (int c = 0; c < ED; ++c) {
        wge[c] = Wg1[(size_t)(2 * SD + c) * ID + k];
        wme[c] = Wm1[(size_t)(2 * SD + c) * ID + k];
    }
    const float hgi = Hgi[(size_t)bi * ID + k];
    const float hmi = Hmi[(size_t)bi * ID + k];
    const float wg2k = Wg2[k];
    const float bg2v = bg2[0];
    float acc = 0.f, gs = 0.f, dsum = 0.f;
    __shared__ float pg[4][TJ];
    __shared__ float pmask[TJ];
    const float* efb = ef + (size_t)bi * NN * ED;
    const float* emb = em + (size_t)bi * NN;
    const float* HgjB = Hgj + (size_t)b * NN * ID;
    const float* HmjB = Hmj + (size_t)b * NN * ID;
    float tt[TJ];
    for (int jt = 0; jt < NN / TJ; ++jt) {
        const int j0 = jt * TJ;
        #pragma unroll
        for (int jj = 0; jj < TJ; ++jj) {
            const int j = j0 + jj;
            const float4* e4 = reinterpret_cast<const float4*>(efb + (size_t)j * ED);
            float zg = hgi + HgjB[(size_t)j * ID + k];
            float zm = hmi + HmjB[(size_t)j * ID + k];
            #pragma unroll
            for (int c4 = 0; c4 < ED / 4; ++c4) {
                const float4 e = e4[c4];
                zg = fmaf(e.x, wge[c4 * 4 + 0], zg); zm = fmaf(e.x, wme[c4 * 4 + 0], zm);
                zg = fmaf(e.y, wge[c4 * 4 + 1], zg); zm = fmaf(e.y, wme[c4 * 4 + 1], zm);
                zg = fmaf(e.z, wge[c4 * 4 + 2], zg); zm = fmaf(e.z, wme[c4 * 4 + 2], zm);
                zg = fmaf(e.w, wge[c4 * 4 + 3], zg); zm = fmaf(e.w, wme[c4 * 4 + 3], zm);
            }
            float p = ftanh(zg) * wg2k;
            tt[jj] = ftanh(zm);
            #pragma unroll
            for (int m = 1; m < 64; m <<= 1) p += __shfl_xor(p, m, 64);
            if (lane == 0) pg[w][jj] = p;
        }
        if (t < TJ) pmask[t] = emb[j0 + t];
        __syncthreads();
        #pragma unroll
        for (int jj = 0; jj < TJ; ++jj) {
            const float pre = pg[0][jj] + pg[1][jj] + pg[2][jj] + pg[3][jj] + bg2v;
            const float m = pmask[jj];
            const float g = m * __builtin_amdgcn_rcpf(1.0f + __expf(-pre));
            acc = fmaf(g, tt[jj], acc);
            gs += g;
            dsum += m;
        }
        __syncthreads();
    }
    T[(size_t)bi * ID + k] = acc;
    if (t == 0) { gsum[bi] = gs; deg[bi] = dsum; }
}

// ---------------------------------------------------------------------------
// K3: agg[bi,d] = (T[bi,:] @ Wm2[:,d] + gsum*bm2[d]) / max(gsum,1)
// grid BN/16, block 256
// ---------------------------------------------------------------------------
__global__ void k3_agg(const float* __restrict__ T, const float* __restrict__ gsum,
                       const float* __restrict__ Wm2, const float* __restrict__ bm2,
                       float* __restrict__ agg) {
    const int tile = blockIdx.x;
    __shared__ float Ts[16][ID];
    __shared__ float gss[16];
    const int t = threadIdx.x;
    const float* Tb = T + (size_t)tile * 16 * ID;
    for (int i = t; i < 16 * ID; i += 256) Ts[i >> 8][i & 255] = Tb[i];
    if (t < 16) gss[t] = gsum[tile * 16 + t];
    __syncthreads();
    const int d = t & 127;
    const int r0 = (t >> 7) * 8;
    float acc[8];
    #pragma unroll
    for (int r = 0; r < 8; ++r) acc[r] = 0.f;
    for (int kk = 0; kk < ID; ++kk) {
        const float wv = Wm2[kk * SD + d];
        #pragma unroll
        for (int r = 0; r < 8; ++r) acc[r] = fmaf(Ts[r0 + r][kk], wv, acc[r]);
    }
    const float bmv = bm2[d];
    #pragma unroll
    for (int r = 0; r < 8; ++r) {
        const float g = gss[r0 + r];
        const float denom = fmaxf(g, 1.0f);
        agg[(size_t)(tile * 16 + r0 + r) * SD + d] =
            (acc[r] + g * bmv) * __builtin_amdgcn_rcpf(denom);
    }
}

// ---------------------------------------------------------------------------
// K4: update MLP (257->256->128, tanh) + residual + LayerNorm
// grid BN/16, block 256
// ---------------------------------------------------------------------------
__global__ void k4_update(const float* __restrict__ h, const float* __restrict__ agg,
                          const float* __restrict__ deg,
                          const float* __restrict__ Wu1, const float* __restrict__ bu1,
                          const float* __restrict__ Wu2, const float* __restrict__ bu2,
                          const float* __restrict__ lnw, const float* __restrict__ lnb,
                          float* __restrict__ out) {
    const int tile = blockIdx.x;
    const int row0 = tile * 16;
    __shared__ float up[16][2 * SD + 1];
    __shared__ float u[16][ID];
    __shared__ float xs[16][SD];
    const int t = threadIdx.x;
    for (int i = t; i < 16 * SD; i += 256) {
        const int r = i >> 7, c = i & 127;
        up[r][c] = h[(size_t)(row0 + r) * SD + c];
        up[r][SD + c] = agg[(size_t)(row0 + r) * SD + c];
    }
    if (t < 16) up[t][2 * SD] = deg[row0 + t] * (1.0f / 127.0f);
    __syncthreads();
    {
        float acc[16];
        const float bk = bu1[t];
        #pragma unroll
        for (int r = 0; r < 16; ++r) acc[r] = bk;
        for (int c = 0; c < 2 * SD + 1; ++c) {
            const float wv = Wu1[c * ID + t];
            #pragma unroll
            for (int r = 0; r < 16; ++r) acc[r] = fmaf(up[r][c], wv, acc[r]);
        }
        #pragma unroll
        for (int r = 0; r < 16; ++r) u[r][t] = ftanh(acc[r]);
    }
    __syncthreads();
    {
        const int d = t & 127;
        const int r0 = (t >> 7) * 8;
        float acc[8];
        const float bd = bu2[d];
        #pragma unroll
        for (int r = 0; r < 8; ++r) acc[r] = bd;
        for (int kk = 0; kk < ID; ++kk) {
            const float wv = Wu2[kk * SD + d];
            #pragma unroll
            for (int r = 0; r < 8; ++r) acc[r] = fmaf(u[r0 + r][kk], wv, acc[r]);
        }
        #pragma unroll
        for (int r = 0; r < 8; ++r) xs[r0 + r][d] = up[r0 + r][d] + ftanh(acc[r]);
    }
    __syncthreads();
    const int w = t >> 6, lane = t & 63;
    #pragma unroll
    for (int rr = 0; rr < 4; ++rr) {
        const int r = w * 4 + rr;
        const float v0 = xs[r][lane], v1 = xs[r][lane + 64];
        float s = v0 + v1;
        #pragma unroll
        for (int m = 1; m < 64; m <<= 1) s += __shfl_xor(s, m, 64);
        const float mu = s * (1.0f / SD);
        const float d0 = v0 - mu, d1 = v1 - mu;
        float q = d0 * d0 + d1 * d1;
        #pragma unroll
        for (int m = 1; m < 64; m <<= 1) q += __shfl_xor(q, m, 64);
        const float inv = rsqrtf(q * (1.0f / SD) + 1e-5f);
        out[(size_t)(row0 + r) * SD + lane] = d0 * inv * lnw[lane] + lnb[lane];
        out[(size_t)(row0 + r) * SD + lane + 64] = d1 * inv * lnw[lane + 64] + lnb[lane + 64];
    }
}

extern "C" void kernel_launch(void* const* d_in, const int* in_sizes, int n_in,
                              void* d_out, int out_size, void* d_ws, size_t ws_size,
                              hipStream_t stream) {
    const float* h   = (const float*)d_in[0];
    const float* ef  = (const float*)d_in[1];
    const float* em  = (const float*)d_in[2];
    const float* Wm1 = (const float*)d_in[3];
    const float* bm1 = (const float*)d_in[4];
    const float* Wm2 = (const float*)d_in[5];
    const float* bm2 = (const float*)d_in[6];
    const float* Wg1 = (const float*)d_in[7];
    const float* bg1 = (const float*)d_in[8];
    const float* Wg2 = (const float*)d_in[9];
    const float* bg2 = (const float*)d_in[10];
    const float* Wu1 = (const float*)d_in[11];
    const float* bu1 = (const float*)d_in[12];
    const float* Wu2 = (const float*)d_in[13];
    const float* bu2 = (const float*)d_in[14];
    const float* lnw = (const float*)d_in[15];
    const float* lnb = (const float*)d_in[16];

    float* ws = (float*)d_ws;
    float* Hgi = ws;
    float* Hgj = Hgi + (size_t)BN * ID;
    float* Hmi = Hgj + (size_t)BN * ID;
    float* Hmj = Hmi + (size_t)BN * ID;
    float* T   = Hmj + (size_t)BN * ID;
    float* gsumv = T + (size_t)BN * ID;
    float* degv  = gsumv + BN;
    float* aggv  = degv + BN;
    float* outp = (float*)d_out;

    k1_preproj<<<dim3(BN / 32, 4), 256, 0, stream>>>(h, Wg1, bg1, Wm1, bm1,
                                                     Hgi, Hgj, Hmi, Hmj);
    k2_edges<<<BN, 256, 0, stream>>>(ef, em, Wg1, Wm1, Wg2, bg2,
                                     Hgi, Hgj, Hmi, Hmj, T, gsumv, degv);
    k3_agg<<<BN / 16, 256, 0, stream>>>(T, gsumv, Wm2, bm2, aggv);
    k4_update<<<BN / 16, 256, 0, stream>>>(h, aggv, degv, Wu1, bu1, Wu2, bu2,
                                           lnw, lnb, outp);
}

// Round 2
// 251.398 us; speedup vs baseline: 2.9672x; 2.9672x over previous
//
#include <hip/hip_runtime.h>
#include <hip/hip_bf16.h>

#define BB 32
#define NN 128
#define SD 128
#define ED 32
#define ID 256
#define BN (BB*NN)   // 4096
#define KH 160       // 128 (h_j) + 32 (e)

typedef __attribute__((ext_vector_type(8))) short sh8;
typedef __attribute__((ext_vector_type(4))) float f32x4;

__device__ __forceinline__ float ftanh(float x) {
    float e2 = __expf(2.0f * x);
    return 1.0f - 2.0f * __builtin_amdgcn_rcpf(e2 + 1.0f);
}

__device__ __forceinline__ ushort f2bf(float f) {
    unsigned u = __float_as_uint(f);
    return (ushort)((u + 0x7FFF + ((u >> 16) & 1)) >> 16);
}

// ---------------------------------------------------------------------------
// prep: Bprep[mat2][nt16][ks5] tiles, 512 u16 each, frag-ordered for MFMA B:
// lane l holds B[k = ks*32 + (l>>4)*8 + e][col = nt*16 + (l&15)], e=0..7
// W rows used: 128..287 of W1 (h_j part 128..255, e part 256..287)
// grid 160, block 64
// ---------------------------------------------------------------------------
__global__ void k_prep_w(const float* __restrict__ Wg1, const float* __restrict__ Wm1,
                         ushort* __restrict__ Bprep) {
    const int tile = blockIdx.x;
    const int l = threadIdx.x;
    const int mat = tile / 80;
    const int rem = tile % 80;
    const int nt = rem / 5, ks = rem % 5;
    const float* W = mat ? Wm1 : Wg1;
    const int col = nt * 16 + (l & 15);
    const int kbase = ks * 32 + (l >> 4) * 8;
    sh8 v;
    #pragma unroll
    for (int e = 0; e < 8; ++e)
        v[e] = (short)f2bf(W[(size_t)(128 + kbase + e) * ID + col]);
    *(sh8*)&Bprep[(size_t)tile * 512 + l * 8] = v;
}

// ---------------------------------------------------------------------------
// K1: i-side projections (f32): H{g,m}i[n,k] = h[n,:] @ W1[0:128,k] + b1[k]
// plus hbf = bf16(h). grid (BN/32, 2), block 256
// ---------------------------------------------------------------------------
__global__ void k1_preproj(const float* __restrict__ h,
                           const float* __restrict__ Wg1, const float* __restrict__ bg1,
                           const float* __restrict__ Wm1, const float* __restrict__ bm1,
                           float* __restrict__ Hgi, float* __restrict__ Hmi,
                           ushort* __restrict__ hbf) {
    const int tile = blockIdx.x;
    const int which = blockIdx.y;
    __shared__ float hs[32][SD];
    const int t = threadIdx.x;
    const float* hrow = h + (size_t)tile * 32 * SD;
    for (int i = t; i < 32 * SD; i += 256) hs[i >> 7][i & 127] = hrow[i];
    __syncthreads();
    if (which == 0) {
        for (int i = t; i < 32 * SD; i += 256)
            hbf[(size_t)tile * 32 * SD + i] = f2bf(hs[i >> 7][i & 127]);
    }
    const float* W = which ? Wm1 : Wg1;
    const float* bias = which ? bm1 : bg1;
    float* out = which ? Hmi : Hgi;
    const int k = t;
    float acc[32];
    const float b0 = bias[k];
    #pragma unroll
    for (int r = 0; r < 32; ++r) acc[r] = b0;
    for (int c = 0; c < SD; ++c) {
        const float wv = W[c * ID + k];
        #pragma unroll
        for (int r = 0; r < 32; ++r) acc[r] = fmaf(hs[r][c], wv, acc[r]);
    }
    #pragma unroll
    for (int r = 0; r < 32; ++r) out[(size_t)(tile * 32 + r) * ID + k] = acc[r];
}

// ---------------------------------------------------------------------------
// K2: per-(b,i) edge block. MFMA Z[128j,256k] = [h_j|e] @ W  (bf16, K=160),
// + f32 i-side Hi[k]. Gate pass then msg pass; 4 waves, N-split (64 cols/wave).
// A-tiles frag-ordered in LDS (conflict-free ds_read_b128); B frags in VGPRs.
// grid BN, block 256
// ---------------------------------------------------------------------------
__global__ __launch_bounds__(256, 2) void k2_edges(
        const float* __restrict__ ef, const float* __restrict__ em,
        const ushort* __restrict__ hbf, const ushort* __restrict__ Bprep,
        const float* __restrict__ Hgi, const float* __restrict__ Hmi,
        const float* __restrict__ Wg2, const float* __restrict__ bg2,
        float* __restrict__ T, float* __restrict__ gsum, float* __restrict__ deg) {
    const int bi = blockIdx.x;
    const int b = bi >> 7;
    const int t = threadIdx.x;
    const int w = t >> 6;
    const int lane = t & 63;
    const int col = lane & 15;
    const int grp = lane >> 4;

    __shared__ __align__(16) ushort Afrag[40 * 512];  // 8 stripes x 5 ks, 1KB tiles
    __shared__ float gpart[4][NN];
    __shared__ float glds[NN];
    __shared__ float red[4];

    // ---- stage A: h_j part (frag-ordered). tile = stripe*5 + ks
    {
        const ushort* hrow = hbf + (size_t)b * NN * SD;
        #pragma unroll
        for (int it = 0; it < 8; ++it) {
            const int c = it * 256 + t;        // 2048 chunks of 8 bf16
            const int j = c >> 4, k8 = c & 15;
            sh8 v = *(const sh8*)(hrow + j * SD + k8 * 8);
            const int tile = (j >> 4) * 5 + (k8 >> 2);
            const int lp = (k8 & 3) * 16 + (j & 15);
            *(sh8*)&Afrag[tile * 512 + lp * 8] = v;
        }
        // e part: ks = 4
        const float* efb = ef + (size_t)bi * NN * ED;
        #pragma unroll
        for (int it = 0; it < 2; ++it) {
            const int c = it * 256 + t;        // 512 chunks
            const int j = c >> 2, k8 = c & 3;
            const float* p = efb + j * ED + k8 * 8;
            f32x4 a0 = *(const f32x4*)p;
            f32x4 a1 = *(const f32x4*)(p + 4);
            sh8 v;
            v[0] = (short)f2bf(a0[0]); v[1] = (short)f2bf(a0[1]);
            v[2] = (short)f2bf(a0[2]); v[3] = (short)f2bf(a0[3]);
            v[4] = (short)f2bf(a1[0]); v[5] = (short)f2bf(a1[1]);
            v[6] = (short)f2bf(a1[2]); v[7] = (short)f2bf(a1[3]);
            const int tile = (j >> 4) * 5 + 4;
            const int lp = k8 * 16 + (j & 15);
            *(sh8*)&Afrag[tile * 512 + lp * 8] = v;
        }
    }
    __syncthreads();

    // ================= gate pass (mat 0), wave w owns cols [w*64, w*64+64)
    {
        sh8 Bf[20];
        const ushort* bp = Bprep + (size_t)(w * 4 * 5) * 512;
        #pragma unroll
        for (int i = 0; i < 20; ++i)
            Bf[i] = *(const sh8*)(bp + (size_t)i * 512 + lane * 8);
        float hgi_r[4], wg2_r[4];
        #pragma unroll
        for (int n = 0; n < 4; ++n) {
            hgi_r[n] = Hgi[(size_t)bi * ID + (w * 4 + n) * 16 + col];
            wg2_r[n] = Wg2[(w * 4 + n) * 16 + col];
        }
        for (int s = 0; s < 8; ++s) {
            sh8 Af[5];
            #pragma unroll
            for (int ks = 0; ks < 5; ++ks)
                Af[ks] = *(const sh8*)&Afrag[(s * 5 + ks) * 512 + lane * 8];
            f32x4 acc[4];
            #pragma unroll
            for (int n = 0; n < 4; ++n) acc[n] = (f32x4){0.f, 0.f, 0.f, 0.f};
            #pragma unroll
            for (int n = 0; n < 4; ++n)
                #pragma unroll
                for (int ks = 0; ks < 5; ++ks)
                    acc[n] = __builtin_amdgcn_mfma_f32_16x16x32_bf16(
                        Af[ks], Bf[n * 5 + ks], acc[n], 0, 0, 0);
            float p[4] = {0.f, 0.f, 0.f, 0.f};
            #pragma unroll
            for (int n = 0; n < 4; ++n)
                #pragma unroll
                for (int r = 0; r < 4; ++r)
                    p[r] = fmaf(ftanh(acc[n][r] + hgi_r[n]), wg2_r[n], p[r]);
            #pragma unroll
            for (int m = 1; m < 16; m <<= 1)
                #pragma unroll
                for (int r = 0; r < 4; ++r) p[r] += __shfl_xor(p[r], m, 64);
            if (col == 0) {
                #pragma unroll
                for (int r = 0; r < 4; ++r) gpart[w][s * 16 + grp * 4 + r] = p[r];
            }
        }
    }
    __syncthreads();

    // ---- g[j] = mask * sigmoid(sum + bg2); gs, deg reductions
    if (t < NN) {
        const float pre = gpart[0][t] + gpart[1][t] + gpart[2][t] + gpart[3][t] + bg2[0];
        const float m = em[(size_t)bi * NN + t];
        const float g = m * __builtin_amdgcn_rcpf(1.0f + __expf(-pre));
        glds[t] = g;
        float gsv = g, dv = m;
        #pragma unroll
        for (int mm = 1; mm < 64; mm <<= 1) {
            gsv += __shfl_xor(gsv, mm, 64);
            dv  += __shfl_xor(dv, mm, 64);
        }
        if (lane == 0) { red[w * 2] = gsv; red[w * 2 + 1] = dv; }
    }
    __syncthreads();
    if (t == 0) { gsum[bi] = red[0] + red[2]; deg[bi] = red[1] + red[3]; }

    // ================= msg pass (mat 1)
    {
        sh8 Bf[20];
        const ushort* bp = Bprep + (size_t)(80 + w * 4 * 5) * 512;
        #pragma unroll
        for (int i = 0; i < 20; ++i)
            Bf[i] = *(const sh8*)(bp + (size_t)i * 512 + lane * 8);
        float hmi_r[4];
        #pragma unroll
        for (int n = 0; n < 4; ++n)
            hmi_r[n] = Hmi[(size_t)bi * ID + (w * 4 + n) * 16 + col];
        float ts[4] = {0.f, 0.f, 0.f, 0.f};
        for (int s = 0; s < 8; ++s) {
            sh8 Af[5];
            #pragma unroll
            for (int ks = 0; ks < 5; ++ks)
                Af[ks] = *(const sh8*)&Afrag[(s * 5 + ks) * 512 + lane * 8];
            f32x4 acc[4];
            #pragma unroll
            for (int n = 0; n < 4; ++n) acc[n] = (f32x4){0.f, 0.f, 0.f, 0.f};
            #pragma unroll
            for (int n = 0; n < 4; ++n)
                #pragma unroll
                for (int ks = 0; ks < 5; ++ks)
                    acc[n] = __builtin_amdgcn_mfma_f32_16x16x32_bf16(
                        Af[ks], Bf[n * 5 + ks], acc[n], 0, 0, 0);
            float gr[4];
            #pragma unroll
            for (int r = 0; r < 4; ++r) gr[r] = glds[s * 16 + grp * 4 + r];
            #pragma unroll
            for (int n = 0; n < 4; ++n)
                #pragma unroll
                for (int r = 0; r < 4; ++r)
                    ts[n] = fmaf(gr[r], ftanh(acc[n][r] + hmi_r[n]), ts[n]);
        }
        #pragma unroll
        for (int n = 0; n < 4; ++n) {
            ts[n] += __shfl_xor(ts[n], 16, 64);
            ts[n] += __shfl_xor(ts[n], 32, 64);
        }
        if (lane < 16) {
            #pragma unroll
            for (int n = 0; n < 4; ++n)
                T[(size_t)bi * ID + (w * 4 + n) * 16 + lane] = ts[n];
        }
    }
}

// ---------------------------------------------------------------------------
// K3: agg[bi,d] = (T[bi,:] @ Wm2[:,d] + gsum*bm2[d]) / max(gsum,1)
// grid BN/16, block 256
// ---------------------------------------------------------------------------
__global__ void k3_agg(const float* __restrict__ T, const float* __restrict__ gsum,
                       const float* __restrict__ Wm2, const float* __restrict__ bm2,
                       float* __restrict__ agg) {
    const int tile = blockIdx.x;
    __shared__ float Ts[16][ID];
    __shared__ float gss[16];
    const int t = threadIdx.x;
    const float* Tb = T + (size_t)tile * 16 * ID;
    for (int i = t; i < 16 * ID; i += 256) Ts[i >> 8][i & 255] = Tb[i];
    if (t < 16) gss[t] = gsum[tile * 16 + t];
    __syncthreads();
    const int d = t & 127;
    const int r0 = (t >> 7) * 8;
    float acc[8];
    #pragma unroll
    for (int r = 0; r < 8; ++r) acc[r] = 0.f;
    for (int kk = 0; kk < ID; ++kk) {
        const float wv = Wm2[kk * SD + d];
        #pragma unroll
        for (int r = 0; r < 8; ++r) acc[r] = fmaf(Ts[r0 + r][kk], wv, acc[r]);
    }
    const float bmv = bm2[d];
    #pragma unroll
    for (int r = 0; r < 8; ++r) {
        const float g = gss[r0 + r];
        const float denom = fmaxf(g, 1.0f);
        agg[(size_t)(tile * 16 + r0 + r) * SD + d] =
            (acc[r] + g * bmv) * __builtin_amdgcn_rcpf(denom);
    }
}

// ---------------------------------------------------------------------------
// K4: update MLP (257->256->128, tanh) + residual + LayerNorm
// grid BN/16, block 256
// ---------------------------------------------------------------------------
__global__ void k4_update(const float* __restrict__ h, const float* __restrict__ agg,
                          const float* __restrict__ deg,
                          const float* __restrict__ Wu1, const float* __restrict__ bu1,
                          const float* __restrict__ Wu2, const float* __restrict__ bu2,
                          const float* __restrict__ lnw, const float* __restrict__ lnb,
                          float* __restrict__ out) {
    const int tile = blockIdx.x;
    const int row0 = tile * 16;
    __shared__ float up[16][2 * SD + 1];
    __shared__ float u[16][ID];
    __shared__ float xs[16][SD];
    const int t = threadIdx.x;
    for (int i = t; i < 16 * SD; i += 256) {
        const int r = i >> 7, c = i & 127;
        up[r][c] = h[(size_t)(row0 + r) * SD + c];
        up[r][SD + c] = agg[(size_t)(row0 + r) * SD + c];
    }
    if (t < 16) up[t][2 * SD] = deg[row0 + t] * (1.0f / 127.0f);
    __syncthreads();
    {
        float acc[16];
        const float bk = bu1[t];
        #pragma unroll
        for (int r = 0; r < 16; ++r) acc[r] = bk;
        for (int c = 0; c < 2 * SD + 1; ++c) {
            const float wv = Wu1[c * ID + t];
            #pragma unroll
            for (int r = 0; r < 16; ++r) acc[r] = fmaf(up[r][c], wv, acc[r]);
        }
        #pragma unroll
        for (int r = 0; r < 16; ++r) u[r][t] = ftanh(acc[r]);
    }
    __syncthreads();
    {
        const int d = t & 127;
        const int r0 = (t >> 7) * 8;
        float acc[8];
        const float bd = bu2[d];
        #pragma unroll
        for (int r = 0; r < 8; ++r) acc[r] = bd;
        for (int kk = 0; kk < ID; ++kk) {
            const float wv = Wu2[kk * SD + d];
            #pragma unroll
            for (int r = 0; r < 8; ++r) acc[r] = fmaf(u[r0 + r][kk], wv, acc[r]);
        }
        #pragma unroll
        for (int r = 0; r < 8; ++r) xs[r0 + r][d] = up[r0 + r][d] + ftanh(acc[r]);
    }
    __syncthreads();
    const int w = t >> 6, lane = t & 63;
    #pragma unroll
    for (int rr = 0; rr < 4; ++rr) {
        const int r = w * 4 + rr;
        const float v0 = xs[r][lane], v1 = xs[r][lane + 64];
        float s = v0 + v1;
        #pragma unroll
        for (int m = 1; m < 64; m <<= 1) s += __shfl_xor(s, m, 64);
        const float mu = s * (1.0f / SD);
        const float d0 = v0 - mu, d1 = v1 - mu;
        float q = d0 * d0 + d1 * d1;
        #pragma unroll
        for (int m = 1; m < 64; m <<= 1) q += __shfl_xor(q, m, 64);
        const float inv = rsqrtf(q * (1.0f / SD) + 1e-5f);
        out[(size_t)(row0 + r) * SD + lane] = d0 * inv * lnw[lane] + lnb[lane];
        out[(size_t)(row0 + r) * SD + lane + 64] = d1 * inv * lnw[lane + 64] + lnb[lane + 64];
    }
}

extern "C" void kernel_launch(void* const* d_in, const int* in_sizes, int n_in,
                              void* d_out, int out_size, void* d_ws, size_t ws_size,
                              hipStream_t stream) {
    const float* h   = (const float*)d_in[0];
    const float* ef  = (const float*)d_in[1];
    const float* em  = (const float*)d_in[2];
    const float* Wm1 = (const float*)d_in[3];
    const float* bm1 = (const float*)d_in[4];
    const float* Wm2 = (const float*)d_in[5];
    const float* bm2 = (const float*)d_in[6];
    const float* Wg1 = (const float*)d_in[7];
    const float* bg1 = (const float*)d_in[8];
    const float* Wg2 = (const float*)d_in[9];
    const float* bg2 = (const float*)d_in[10];
    const float* Wu1 = (const float*)d_in[11];
    const float* bu1 = (const float*)d_in[12];
    const float* Wu2 = (const float*)d_in[13];
    const float* bu2 = (const float*)d_in[14];
    const float* lnw = (const float*)d_in[15];
    const float* lnb = (const float*)d_in[16];

    float* ws = (float*)d_ws;
    float* Hgi   = ws;
    float* Hmi   = Hgi + (size_t)BN * ID;
    float* T     = Hmi + (size_t)BN * ID;
    float* aggv  = T + (size_t)BN * ID;
    float* gsumv = aggv + (size_t)BN * SD;
    float* degv  = gsumv + BN;
    ushort* hbf   = (ushort*)(degv + BN);
    ushort* Bprep = hbf + (size_t)BN * SD;
    float* outp = (float*)d_out;

    k_prep_w<<<160, 64, 0, stream>>>(Wg1, Wm1, Bprep);
    k1_preproj<<<dim3(BN / 32, 2), 256, 0, stream>>>(h, Wg1, bg1, Wm1, bm1,
                                                     Hgi, Hmi, hbf);
    k2_edges<<<BN, 256, 0, stream>>>(ef, em, hbf, Bprep, Hgi, Hmi, Wg2, bg2,
                                     T, gsumv, degv);
    k3_agg<<<BN / 16, 256, 0, stream>>>(T, gsumv, Wm2, bm2, aggv);
    k4_update<<<BN / 16, 256, 0, stream>>>(h, aggv, degv, Wu1, bu1, Wu2, bu2,
                                           lnw, lnb, outp);
}